// Round 1
// baseline (3303.695 us; speedup 1.0000x reference)
//
#include <hip/hip_runtime.h>
#include <hip/hip_bf16.h>

// Problem constants
#define B_    8
#define CIN   256
#define COUT  256
#define KK    3
#define H_    128
#define W_    128

// Conv tile config
#define TH    8      // output rows per block
#define OCB   8      // output channels per block
#define LDSROW 133   // padded LDS row stride (odd-ish vs 32 banks; cols used: 130)

__device__ __forceinline__ float leaky(float v) {
    return v >= 0.f ? v : 0.2f * v;
}

// S[i][kw] = sum_{o,kh} weight[o,i,kh,kw]^2          (grid = CIN blocks, 256 thr)
__global__ void compute_S_kernel(const float* __restrict__ weight, float* __restrict__ S) {
    const int i = blockIdx.x;      // cin
    const int t = threadIdx.x;     // = o (COUT == 256 == blockDim)
    const float* wp = weight + ((size_t)t * CIN + i) * (KK * KK);
    float s0 = 0.f, s1 = 0.f, s2 = 0.f;
#pragma unroll
    for (int kh = 0; kh < 3; ++kh) {
        float a = wp[kh * 3 + 0], b = wp[kh * 3 + 1], c = wp[kh * 3 + 2];
        s0 = fmaf(a, a, s0);
        s1 = fmaf(b, b, s1);
        s2 = fmaf(c, c, s2);
    }
    __shared__ float red[3][256];
    red[0][t] = s0; red[1][t] = s1; red[2][t] = s2;
    __syncthreads();
    for (int off = 128; off > 0; off >>= 1) {
        if (t < off) {
            red[0][t] += red[0][t + off];
            red[1][t] += red[1][t + off];
            red[2][t] += red[2][t + off];
        }
        __syncthreads();
    }
    if (t == 0) {
        S[i * 3 + 0] = red[0][0];
        S[i * 3 + 1] = red[1][0];
        S[i * 3 + 2] = red[2][0];
    }
}

// demod[b][kw] = rsqrt(sum_i style[b,i]^2 * S[i,kw] + 1e-8)   (grid = B blocks)
__global__ void compute_demod_kernel(const float* __restrict__ style,
                                     const float* __restrict__ S,
                                     float* __restrict__ demod) {
    const int b = blockIdx.x;
    const int t = threadIdx.x;     // = i
    float sv = style[b * CIN + t];
    float sv2 = sv * sv;
    float s0 = sv2 * S[t * 3 + 0];
    float s1 = sv2 * S[t * 3 + 1];
    float s2 = sv2 * S[t * 3 + 2];
    __shared__ float red[3][256];
    red[0][t] = s0; red[1][t] = s1; red[2][t] = s2;
    __syncthreads();
    for (int off = 128; off > 0; off >>= 1) {
        if (t < off) {
            red[0][t] += red[0][t + off];
            red[1][t] += red[1][t + off];
            red[2][t] += red[2][t + off];
        }
        __syncthreads();
    }
    if (t == 0) {
        demod[b * 3 + 0] = rsqrtf(red[0][0] + 1e-8f);
        demod[b * 3 + 1] = rsqrtf(red[1][0] + 1e-8f);
        demod[b * 3 + 2] = rsqrtf(red[2][0] + 1e-8f);
    }
}

// wmod[b][i][o][j] = weight[o][i][j] * style[b][i] * demod[b][j%3]   (j = kh*3+kw)
__global__ void compute_wmod_kernel(const float* __restrict__ weight,
                                    const float* __restrict__ style,
                                    const float* __restrict__ demod,
                                    float* __restrict__ wmod) {
    const int t = blockIdx.x * 256 + threadIdx.x;   // linear over [b][i][o][9]
    const int j = t % 9;
    const int o = (t / 9) & (COUT - 1);
    const int i = (t / (9 * COUT)) & (CIN - 1);
    const int b = t / (9 * COUT * CIN);
    float w = weight[((size_t)o * CIN + i) * 9 + j];
    float m = style[b * CIN + i] * demod[b * 3 + (j % 3)];
    wmod[t] = w * m;
}

// Direct conv + leaky relu.
// Block: (b, oc0=8 channels, h0=8 rows); 256 threads; thread = (row ry, 4-px strip c0).
__global__ __launch_bounds__(256) void conv_kernel(const float* __restrict__ x,
                                                   const float* __restrict__ wmod,
                                                   float* __restrict__ out) {
    const int b   = blockIdx.z;
    const int oc0 = blockIdx.y * OCB;
    const int h0  = blockIdx.x * TH;
    const int tid = threadIdx.x;

    __shared__ float lds_in[10 * LDSROW];  // rows h0-1..h0+8, cols -1..128 (130 used)
    __shared__ float lds_w[OCB * 12];      // [o][kh*3+kw] padded to 12

    const int ry = tid >> 5;          // 0..7 output row within tile
    const int c0 = (tid & 31) << 2;   // 0,4,...,124 output col base

    float acc[OCB][4];
#pragma unroll
    for (int o = 0; o < OCB; ++o)
#pragma unroll
        for (int p = 0; p < 4; ++p) acc[o][p] = 0.f;

    for (int i = 0; i < CIN; ++i) {
        // stage input tile (with zero halo)
        const float* xp = x + ((size_t)(b * CIN + i)) * (H_ * W_);
        for (int idx = tid; idx < 10 * 130; idx += 256) {
            int r = idx / 130;
            int c = idx - r * 130;
            int gh = h0 - 1 + r;
            int gw = c - 1;
            float v = 0.f;
            if ((unsigned)gh < H_ && (unsigned)gw < W_) v = xp[gh * W_ + gw];
            lds_in[r * LDSROW + c] = v;
        }
        // stage weights: 72 contiguous floats for (b, i, oc0..oc0+7)
        if (tid < OCB * 9) {
            int o = tid / 9;
            int j = tid - o * 9;
            lds_w[o * 12 + j] =
                wmod[(((size_t)b * CIN + i) * COUT + oc0) * 9 + tid];
        }
        __syncthreads();

        float xin[3][6];
#pragma unroll
        for (int dr = 0; dr < 3; ++dr)
#pragma unroll
            for (int dc = 0; dc < 6; ++dc)
                xin[dr][dc] = lds_in[(ry + dr) * LDSROW + c0 + dc];

#pragma unroll
        for (int o = 0; o < OCB; ++o) {
#pragma unroll
            for (int kh = 0; kh < 3; ++kh) {
                float w0 = lds_w[o * 12 + kh * 3 + 0];
                float w1 = lds_w[o * 12 + kh * 3 + 1];
                float w2 = lds_w[o * 12 + kh * 3 + 2];
#pragma unroll
                for (int p = 0; p < 4; ++p) {
                    acc[o][p] = fmaf(xin[kh][p + 0], w0, acc[o][p]);
                    acc[o][p] = fmaf(xin[kh][p + 1], w1, acc[o][p]);
                    acc[o][p] = fmaf(xin[kh][p + 2], w2, acc[o][p]);
                }
            }
        }
        __syncthreads();
    }

    // epilogue: leaky relu + vectorized store
#pragma unroll
    for (int o = 0; o < OCB; ++o) {
        float4 v;
        v.x = leaky(acc[o][0]);
        v.y = leaky(acc[o][1]);
        v.z = leaky(acc[o][2]);
        v.w = leaky(acc[o][3]);
        *(float4*)&out[(((size_t)b * COUT + (oc0 + o)) * H_ + (h0 + ry)) * W_ + c0] = v;
    }
}

extern "C" void kernel_launch(void* const* d_in, const int* in_sizes, int n_in,
                              void* d_out, int out_size, void* d_ws, size_t ws_size,
                              hipStream_t stream) {
    const float* x      = (const float*)d_in[0];  // (8,256,128,128)
    const float* style  = (const float*)d_in[1];  // (8,256)
    const float* weight = (const float*)d_in[2];  // (256,256,3,3)
    float* out = (float*)d_out;                   // (8,256,128,128)

    // workspace layout (fp32): S[256*3] | demod[8*3] | pad | wmod[8*256*256*9]
    float* S     = (float*)d_ws;
    float* demod = S + 256 * 3;
    float* wmod  = (float*)d_ws + 1024;           // 4 KiB offset; needs ~18.9 MB ws

    compute_S_kernel<<<CIN, 256, 0, stream>>>(weight, S);
    compute_demod_kernel<<<B_, 256, 0, stream>>>(style, S, demod);
    compute_wmod_kernel<<<(B_ * CIN * COUT * 9) / 256, 256, 0, stream>>>(
        weight, style, demod, wmod);
    conv_kernel<<<dim3(H_ / TH, COUT / OCB, B_), 256, 0, stream>>>(x, wmod, out);
}

// Round 2
// 324.845 us; speedup vs baseline: 10.1701x; 10.1701x over previous
//
#include <hip/hip_runtime.h>
#include <hip/hip_bf16.h>

// Problem constants
#define B_    8
#define CIN   256
#define COUT  256
#define H_    128
#define W_    128
#define HP    130   // padded
#define WP    130

using bfrag = __attribute__((ext_vector_type(8))) short;   // 8 bf16 (4 VGPRs)
using f32x4 = __attribute__((ext_vector_type(4))) float;   // 4 fp32 acc

__device__ __forceinline__ float leaky(float v) {
    return v >= 0.f ? v : 0.2f * v;
}

__device__ __forceinline__ unsigned short to_bf16(float v) {
    __hip_bfloat16 h = __float2bfloat16(v);
    return *(unsigned short*)&h;
}

// ---------------------------------------------------------------------------
// S[i][kw] = sum_{o,kh} weight[o,i,kh,kw]^2          (grid = CIN, 256 thr)
__global__ void compute_S_kernel(const float* __restrict__ weight, float* __restrict__ S) {
    const int i = blockIdx.x;
    const int t = threadIdx.x;     // = o
    const float* wp = weight + ((size_t)t * CIN + i) * 9;
    float s0 = 0.f, s1 = 0.f, s2 = 0.f;
#pragma unroll
    for (int kh = 0; kh < 3; ++kh) {
        float a = wp[kh * 3 + 0], b = wp[kh * 3 + 1], c = wp[kh * 3 + 2];
        s0 = fmaf(a, a, s0); s1 = fmaf(b, b, s1); s2 = fmaf(c, c, s2);
    }
    __shared__ float red[3][256];
    red[0][t] = s0; red[1][t] = s1; red[2][t] = s2;
    __syncthreads();
    for (int off = 128; off > 0; off >>= 1) {
        if (t < off) {
            red[0][t] += red[0][t + off];
            red[1][t] += red[1][t + off];
            red[2][t] += red[2][t + off];
        }
        __syncthreads();
    }
    if (t == 0) {
        S[i * 3 + 0] = red[0][0];
        S[i * 3 + 1] = red[1][0];
        S[i * 3 + 2] = red[2][0];
    }
}

// demod[b][kw] = rsqrt(sum_i style[b,i]^2 * S[i,kw] + 1e-8)   (grid = B)
__global__ void compute_demod_kernel(const float* __restrict__ style,
                                     const float* __restrict__ S,
                                     float* __restrict__ demod) {
    const int b = blockIdx.x;
    const int t = threadIdx.x;     // = i
    float sv = style[b * CIN + t];
    float sv2 = sv * sv;
    float s0 = sv2 * S[t * 3 + 0];
    float s1 = sv2 * S[t * 3 + 1];
    float s2 = sv2 * S[t * 3 + 2];
    __shared__ float red[3][256];
    red[0][t] = s0; red[1][t] = s1; red[2][t] = s2;
    __syncthreads();
    for (int off = 128; off > 0; off >>= 1) {
        if (t < off) {
            red[0][t] += red[0][t + off];
            red[1][t] += red[1][t + off];
            red[2][t] += red[2][t + off];
        }
        __syncthreads();
    }
    if (t == 0) {
        demod[b * 3 + 0] = rsqrtf(red[0][0] + 1e-8f);
        demod[b * 3 + 1] = rsqrtf(red[1][0] + 1e-8f);
        demod[b * 3 + 2] = rsqrtf(red[2][0] + 1e-8f);
    }
}

// wT[b][j][o][i] (bf16) = weight[o][i][j] * style[b][i] * demod[b][j%3]
// grid = B*9*COUT blocks, 256 threads (thread = i)
__global__ void compute_wmodT_kernel(const float* __restrict__ weight,
                                     const float* __restrict__ style,
                                     const float* __restrict__ demod,
                                     unsigned short* __restrict__ wT) {
    const int bx = blockIdx.x;
    const int i  = threadIdx.x;
    const int o  = bx & (COUT - 1);
    const int j  = (bx >> 8) % 9;
    const int b  = bx / (9 * COUT);
    float w = weight[((size_t)o * CIN + i) * 9 + j];
    float m = style[b * CIN + i] * demod[b * 3 + (j % 3)];
    wT[(((size_t)(b * 9 + j) * COUT + o)) * CIN + i] = to_bf16(w * m);
}

// NCHW fp32 -> padded NHWC bf16: xT[b][h+1][w+1][i] = bf16(x[b][i][h][w])
// grid = dim3(4*8, 128, 8): x -> (wtile = x&3, itile = x>>2); 256 threads
__global__ __launch_bounds__(256) void transpose_kernel(const float* __restrict__ x,
                                                        unsigned short* __restrict__ xT) {
    const int bx = blockIdx.x;
    const int wtile = (bx & 3) * 32;
    const int itile = (bx >> 2) * 32;
    const int h = blockIdx.y;
    const int b = blockIdx.z;
    const int t = threadIdx.x;

    __shared__ float lt[32][33];

    {   // coalesced read: consecutive t -> consecutive w
        const int tw = t & 31, tr = t >> 5;
#pragma unroll
        for (int rr = 0; rr < 4; ++rr) {
            int il = tr + rr * 8;
            lt[il][tw] = x[(((size_t)b * CIN + itile + il) * H_ + h) * W_ + wtile + tw];
        }
    }
    __syncthreads();
    {   // coalesced write: consecutive t -> consecutive i
        const int il = t & 31, wr = t >> 5;
#pragma unroll
        for (int rr = 0; rr < 4; ++rr) {
            int wl = wr + rr * 8;
            xT[(((size_t)b * HP + (h + 1)) * WP + (wtile + wl + 1)) * CIN + itile + il] =
                to_bf16(lt[il][wl]);
        }
    }
}

// ---------------------------------------------------------------------------
// Implicit-GEMM conv + leaky relu.
// Block: 256 thr = 4 waves. Tile: 128 oc x (8 rows x 16 cols) pixels.
// Wave (wm,wn): 64 oc x (4 rows x 16 cols);  m=4 x n=4 fragments of 16x16.
// K-loop: cin chunks of 32; taps grouped by kh (A-tile = [3 kw][128 oc][32 i]).
#define RT   8
#define CTW  16
#define OCT  128
#define APAD 40   // i-stride of lds_a in shorts (80 B: 16B-aligned, ~2-way banks)

__global__ __launch_bounds__(256) void conv_mfma_kernel(
    const unsigned short* __restrict__ xT,   // [8][130][130][256] bf16
    const unsigned short* __restrict__ wT,   // [8][9][256][256]  bf16
    float* __restrict__ out)
{
    const int tid = threadIdx.x;
    const int b   = blockIdx.z;
    const int oc0 = blockIdx.y * OCT;
    const int ph  = blockIdx.x >> 3;          // 0..15
    const int pw  = blockIdx.x & 7;           // 0..7
    const int h0  = ph * RT, w0 = pw * CTW;

    const int wid   = tid >> 6;
    const int lane  = tid & 63;
    const int wm    = wid >> 1;               // 0..1: oc half
    const int wn    = wid & 1;                // 0..1: row half
    const int l15   = lane & 15;
    const int khalf = lane >> 4;              // 0..3

    __shared__ unsigned short lds_x[10 * 18 * 32];     // [r][c][i]   11520 B
    __shared__ unsigned short lds_a[3 * OCT * APAD];   // [kw][o][i]  30720 B

    f32x4 acc[4][4];
#pragma unroll
    for (int m = 0; m < 4; ++m)
#pragma unroll
        for (int n = 0; n < 4; ++n) acc[m][n] = (f32x4){0.f, 0.f, 0.f, 0.f};

    // padded-coord bases: output (h,w) + tap (kh,kw) reads xpad[h+kh][w+kw]
    const unsigned short* xb = xT + ((size_t)b * HP * WP + (size_t)h0 * WP + w0) * CIN;
    const unsigned short* wb = wT + (((size_t)b * 9) * COUT + oc0) * CIN;

    for (int i0 = 0; i0 < CIN; i0 += 32) {
        if (i0) __syncthreads();
        // ---- stage x-tile: 10x18 pixels x 32 ch = 720 x 16B chunks
#pragma unroll
        for (int rep = 0; rep < 3; ++rep) {
            int idx = tid + rep * 256;
            if (idx < 720) {
                int pix = idx >> 2, q = idx & 3;
                int r = pix / 18, c = pix - r * 18;
                int4 v = *(const int4*)(xb + ((size_t)(r * WP + c)) * CIN + i0 + q * 8);
                *(int4*)&lds_x[idx * 8] = v;
            }
        }
        for (int kh = 0; kh < 3; ++kh) {
            if (kh) __syncthreads();
            // ---- stage A-group: [3 kw][128 oc][32 i] = 1536 x 16B chunks
#pragma unroll
            for (int rep = 0; rep < 6; ++rep) {
                int idx = tid + rep * 256;
                int q = idx & 3, o = (idx >> 2) & 127, kw = idx >> 9;
                int4 v = *(const int4*)(wb + ((size_t)((kh * 3 + kw) * COUT + o)) * CIN + i0 + q * 8);
                *(int4*)&lds_a[(kw * OCT + o) * APAD + q * 8] = v;
            }
            __syncthreads();
            // ---- compute: 3 kw x 4 m x 4 n MFMAs
#pragma unroll
            for (int kw = 0; kw < 3; ++kw) {
                bfrag aF[4];
#pragma unroll
                for (int m = 0; m < 4; ++m)
                    aF[m] = *(const bfrag*)&lds_a[(kw * OCT + wm * 64 + m * 16 + l15) * APAD + khalf * 8];
#pragma unroll
                for (int n = 0; n < 4; ++n) {
                    int r = wn * 4 + n + kh;
                    int c = l15 + kw;
                    bfrag bF = *(const bfrag*)&lds_x[((r * 18 + c) * 32) + khalf * 8];
#pragma unroll
                    for (int m = 0; m < 4; ++m)
                        acc[m][n] = __builtin_amdgcn_mfma_f32_16x16x32_bf16(aF[m], bF, acc[m][n], 0, 0, 0);
                }
            }
        }
    }

    // ---- epilogue: leaky relu + store (C/D: col=lane&15, row=(lane>>4)*4+reg)
#pragma unroll
    for (int m = 0; m < 4; ++m) {
#pragma unroll
        for (int n = 0; n < 4; ++n) {
            int h = h0 + wn * 4 + n;
            int w = w0 + l15;
#pragma unroll
            for (int r = 0; r < 4; ++r) {
                int oc = oc0 + wm * 64 + m * 16 + khalf * 4 + r;
                out[(((size_t)b * COUT + oc) * H_ + h) * W_ + w] = leaky(acc[m][n][r]);
            }
        }
    }
}

// ---------------------------------------------------------------------------
extern "C" void kernel_launch(void* const* d_in, const int* in_sizes, int n_in,
                              void* d_out, int out_size, void* d_ws, size_t ws_size,
                              hipStream_t stream) {
    const float* x      = (const float*)d_in[0];  // (8,256,128,128)
    const float* style  = (const float*)d_in[1];  // (8,256)
    const float* weight = (const float*)d_in[2];  // (256,256,3,3)
    float* out = (float*)d_out;                   // (8,256,128,128)

    // ws layout: S f32[768] @0 | demod f32[24] @4096 | wT bf16 @8192 (9.4MB)
    //            | xTpad bf16 @9445376 (69.2MB)   -> total ~78.7 MB
    float* S     = (float*)d_ws;
    float* demod = (float*)((char*)d_ws + 4096);
    unsigned short* wT = (unsigned short*)((char*)d_ws + 8192);
    unsigned short* xT = (unsigned short*)((char*)d_ws + 9445376);

    // zero the padded-NHWC input (border stays zero)
    hipMemsetAsync(xT, 0, (size_t)B_ * HP * WP * CIN * 2, stream);

    compute_S_kernel<<<CIN, 256, 0, stream>>>(weight, S);
    compute_demod_kernel<<<B_, 256, 0, stream>>>(style, S, demod);
    compute_wmodT_kernel<<<B_ * 9 * COUT, 256, 0, stream>>>(weight, style, demod, wT);
    transpose_kernel<<<dim3(32, H_, B_), 256, 0, stream>>>(x, xT);

    conv_mfma_kernel<<<dim3((H_ / RT) * (W_ / CTW), COUT / OCT, B_), 256, 0, stream>>>(
        xT, wT, out);
}

// Round 3
// 212.496 us; speedup vs baseline: 15.5471x; 1.5287x over previous
//
#include <hip/hip_runtime.h>
#include <hip/hip_bf16.h>

// Problem constants
#define B_    8
#define CIN   256
#define COUT  256
#define H_    128
#define W_    128
#define HP    130   // padded
#define WP    130

// Conv tile config
#define RT    8     // output rows per block
#define CT    32    // output cols per block
#define OCT   128   // output channels per block
#define XROWS 10    // RT + 2 halo
#define XCOLS 34    // CT + 2 halo
#define NSTEP 24    // 8 cin-chunks x 3 kh

using bfrag = __attribute__((ext_vector_type(8))) short;   // 8 bf16 (4 VGPRs)
using f32x4 = __attribute__((ext_vector_type(4))) float;   // 4 fp32 acc

__device__ __forceinline__ float leaky(float v) {
    return v >= 0.f ? v : 0.2f * v;
}

__device__ __forceinline__ unsigned short to_bf16(float v) {
    __hip_bfloat16 h = __float2bfloat16(v);
    return *(unsigned short*)&h;
}

// ---------------------------------------------------------------------------
// S[i][kw] = sum_{o,kh} weight[o,i,kh,kw]^2          (grid = CIN, 256 thr)
__global__ void compute_S_kernel(const float* __restrict__ weight, float* __restrict__ S) {
    const int i = blockIdx.x;
    const int t = threadIdx.x;     // = o
    const float* wp = weight + ((size_t)t * CIN + i) * 9;
    float s0 = 0.f, s1 = 0.f, s2 = 0.f;
#pragma unroll
    for (int kh = 0; kh < 3; ++kh) {
        float a = wp[kh * 3 + 0], b = wp[kh * 3 + 1], c = wp[kh * 3 + 2];
        s0 = fmaf(a, a, s0); s1 = fmaf(b, b, s1); s2 = fmaf(c, c, s2);
    }
    __shared__ float red[3][256];
    red[0][t] = s0; red[1][t] = s1; red[2][t] = s2;
    __syncthreads();
    for (int off = 128; off > 0; off >>= 1) {
        if (t < off) {
            red[0][t] += red[0][t + off];
            red[1][t] += red[1][t + off];
            red[2][t] += red[2][t + off];
        }
        __syncthreads();
    }
    if (t == 0) {
        S[i * 3 + 0] = red[0][0];
        S[i * 3 + 1] = red[1][0];
        S[i * 3 + 2] = red[2][0];
    }
}

// demod[b][kw] = rsqrt(sum_i style[b,i]^2 * S[i,kw] + 1e-8)   (grid = B)
__global__ void compute_demod_kernel(const float* __restrict__ style,
                                     const float* __restrict__ S,
                                     float* __restrict__ demod) {
    const int b = blockIdx.x;
    const int t = threadIdx.x;     // = i
    float sv = style[b * CIN + t];
    float sv2 = sv * sv;
    float s0 = sv2 * S[t * 3 + 0];
    float s1 = sv2 * S[t * 3 + 1];
    float s2 = sv2 * S[t * 3 + 2];
    __shared__ float red[3][256];
    red[0][t] = s0; red[1][t] = s1; red[2][t] = s2;
    __syncthreads();
    for (int off = 128; off > 0; off >>= 1) {
        if (t < off) {
            red[0][t] += red[0][t + off];
            red[1][t] += red[1][t + off];
            red[2][t] += red[2][t + off];
        }
        __syncthreads();
    }
    if (t == 0) {
        demod[b * 3 + 0] = rsqrtf(red[0][0] + 1e-8f);
        demod[b * 3 + 1] = rsqrtf(red[1][0] + 1e-8f);
        demod[b * 3 + 2] = rsqrtf(red[2][0] + 1e-8f);
    }
}

// wT[b][j][o][i] (bf16) = weight[o][i][j] * style[b][i] * demod[b][j%3]
// grid = B*9*COUT blocks, 256 threads (thread = i)
__global__ void compute_wmodT_kernel(const float* __restrict__ weight,
                                     const float* __restrict__ style,
                                     const float* __restrict__ demod,
                                     unsigned short* __restrict__ wT) {
    const int bx = blockIdx.x;
    const int i  = threadIdx.x;
    const int o  = bx & (COUT - 1);
    const int j  = (bx >> 8) % 9;
    const int b  = bx / (9 * COUT);
    float w = weight[((size_t)o * CIN + i) * 9 + j];
    float m = style[b * CIN + i] * demod[b * 3 + (j % 3)];
    wT[(((size_t)(b * 9 + j) * COUT + o)) * CIN + i] = to_bf16(w * m);
}

// NCHW fp32 -> padded NHWC bf16: xT[b][h+1][w+1][i] = bf16(x[b][i][h][w])
__global__ __launch_bounds__(256) void transpose_kernel(const float* __restrict__ x,
                                                        unsigned short* __restrict__ xT) {
    const int bx = blockIdx.x;
    const int wtile = (bx & 3) * 32;
    const int itile = (bx >> 2) * 32;
    const int h = blockIdx.y;
    const int b = blockIdx.z;
    const int t = threadIdx.x;

    __shared__ float lt[32][33];

    {   // coalesced read: consecutive t -> consecutive w
        const int tw = t & 31, tr = t >> 5;
#pragma unroll
        for (int rr = 0; rr < 4; ++rr) {
            int il = tr + rr * 8;
            lt[il][tw] = x[(((size_t)b * CIN + itile + il) * H_ + h) * W_ + wtile + tw];
        }
    }
    __syncthreads();
    {   // coalesced write: consecutive t -> consecutive i
        const int il = t & 31, wr = t >> 5;
#pragma unroll
        for (int rr = 0; rr < 4; ++rr) {
            int wl = wr + rr * 8;
            xT[(((size_t)b * HP + (h + 1)) * WP + (wtile + wl + 1)) * CIN + itile + il] =
                to_bf16(lt[il][wl]);
        }
    }
}

// ---------------------------------------------------------------------------
// Implicit-GEMM conv + leaky relu, 2-phase pipelined.
// Block: 512 thr = 8 waves. Tile: 128 oc x (8 rows x 32 cols) pixels.
// Wave (wm, rn, cn): 64 oc x (4 rows x 16 cols); m=4 x n=4 frags of 16x16x32.
// Steps: 24 = 8 cin-chunks(32) x 3 kh. A-tile [3kw][128oc][32i] double-buffered
// via global_load_lds; x-tile [10][34][32i] restaged per cin-chunk.
// LDS XOR swizzle: 16B slot ^= ((row>>1)&3) on source + read (linear gload dest).
__global__ __launch_bounds__(512) void conv_mfma_kernel(
    const unsigned short* __restrict__ xT,   // [8][130][130][256] bf16
    const unsigned short* __restrict__ wT,   // [8][9][256][256]  bf16
    float* __restrict__ out)
{
    const int tid = threadIdx.x;
    const int b   = blockIdx.z;
    const int oc0 = blockIdx.y * OCT;
    const int ph  = blockIdx.x >> 2;          // 0..15
    const int pw  = blockIdx.x & 3;           // 0..3
    const int h0  = ph * RT, w0 = pw * CT;

    const int wid   = tid >> 6;               // 0..7
    const int lane  = tid & 63;
    const int wm    = wid >> 2;               // oc half (64 oc)
    const int rn    = (wid >> 1) & 1;         // row half (4 rows)
    const int cn    = wid & 1;                // col half (16 cols)
    const int l15   = lane & 15;
    const int khalf = lane >> 4;              // k-group 0..3

    __shared__ unsigned short lds_x[XROWS * XCOLS * 32];   // 21760 B, swizzled
    __shared__ unsigned short lds_a[2][3 * OCT * 32];      // 2 x 24576 B, swizzled

    const unsigned short* xb = xT + ((size_t)(b * HP + h0) * WP + w0) * CIN;
    const unsigned short* wb = wT + ((size_t)(b * 9) * COUT + oc0) * CIN;

    f32x4 acc[4][4];
#pragma unroll
    for (int m = 0; m < 4; ++m)
#pragma unroll
        for (int n = 0; n < 4; ++n) acc[m][n] = (f32x4){0.f, 0.f, 0.f, 0.f};

    // ---- x-tile staging: reg round-trip (bounds-free: padded coords), swizzled
    auto stage_X = [&](int i0) {
        for (int idx = tid; idx < XROWS * XCOLS * 4; idx += 512) {
            int pix = idx >> 2, s = idx & 3;
            int r = pix / XCOLS, c = pix - r * XCOLS;
            int q = s ^ ((c >> 1) & 3);
            int4 v = *(const int4*)(xb + (size_t)(r * WP + c) * CIN + i0 + q * 8);
            *(int4*)&lds_x[pix * 32 + s * 8] = v;
        }
    };

    // ---- A-tile staging: global_load_lds width 16, linear dest, source-swizzled
    // wsrc = wT[b][kh*3][oc0][i0]; dst = lds_a[buf]
    auto stage_A = [&](unsigned short* dst, const unsigned short* wsrc) {
#pragma unroll
        for (int j = 0; j < 3; ++j) {
            int c    = (wid * 3 + j) * 64 + lane;   // 16B chunk id in [0,1536)
            int slot = c & 3;
            int o    = (c >> 2) & 127;
            int kw   = c >> 9;
            const unsigned short* src = wsrc + ((size_t)kw * COUT + o) * CIN
                                        + ((slot ^ ((o >> 1) & 3)) << 3);
            __builtin_amdgcn_global_load_lds(
                (const __attribute__((address_space(1))) void*)src,
                (__attribute__((address_space(3))) void*)(dst + (wid * 3 + j) * 512),
                16, 0, 0);
        }
    };

    auto compute = [&](int kh, const unsigned short* abuf) {
#pragma unroll
        for (int kw = 0; kw < 3; ++kw) {
            bfrag aF[4];
#pragma unroll
            for (int m = 0; m < 4; ++m) {
                int oc = wm * 64 + m * 16 + l15;
                aF[m] = *(const bfrag*)&abuf[(kw * OCT + oc) * 32
                          + ((khalf ^ ((oc >> 1) & 3)) << 3)];
            }
#pragma unroll
            for (int n = 0; n < 4; ++n) {
                int row = rn * 4 + n + kh;
                int col = cn * 16 + l15 + kw;
                bfrag bF = *(const bfrag*)&lds_x[(row * XCOLS + col) * 32
                             + ((khalf ^ ((col >> 1) & 3)) << 3)];
#pragma unroll
                for (int m = 0; m < 4; ++m)
                    acc[m][n] = __builtin_amdgcn_mfma_f32_16x16x32_bf16(aF[m], bF, acc[m][n], 0, 0, 0);
            }
        }
    };

    // ---- prologue
    stage_X(0);
    stage_A(lds_a[0], wb);
    __syncthreads();

    // ---- 2-phase main loop: prefetch A(s+1) into alt buffer, compute s
#pragma unroll 1
    for (int s = 0; s < NSTEP; ++s) {
        const int kh = s % 3;
        if (s < NSTEP - 1) {
            const int sn  = s + 1;
            const int khn = sn % 3;
            const int i0n = (sn / 3) * 32;
            stage_A(lds_a[sn & 1], wb + (size_t)(khn * 3) * COUT * CIN + i0n);
        }
        compute(kh, lds_a[s & 1]);
        if (s < NSTEP - 1) {
            if (kh == 2) {                 // cin-chunk rollover: restage x
                __syncthreads();
                stage_X(((s + 1) / 3) * 32);
            }
            __syncthreads();
        }
    }

    // ---- epilogue: leaky relu + store (C/D: col=lane&15 -> pixel, row -> oc)
#pragma unroll
    for (int m = 0; m < 4; ++m) {
#pragma unroll
        for (int n = 0; n < 4; ++n) {
            int h = h0 + rn * 4 + n;
            int w = w0 + cn * 16 + l15;
#pragma unroll
            for (int r = 0; r < 4; ++r) {
                int oc = oc0 + wm * 64 + m * 16 + khalf * 4 + r;
                out[(((size_t)b * COUT + oc) * H_ + h) * W_ + w] = leaky(acc[m][n][r]);
            }
        }
    }
}

// ---------------------------------------------------------------------------
extern "C" void kernel_launch(void* const* d_in, const int* in_sizes, int n_in,
                              void* d_out, int out_size, void* d_ws, size_t ws_size,
                              hipStream_t stream) {
    const float* x      = (const float*)d_in[0];  // (8,256,128,128)
    const float* style  = (const float*)d_in[1];  // (8,256)
    const float* weight = (const float*)d_in[2];  // (256,256,3,3)
    float* out = (float*)d_out;                   // (8,256,128,128)

    // ws layout: S f32[768] @0 | demod f32[24] @4096 | wT bf16 @8192 (9.4MB)
    //            | xTpad bf16 @9445376 (69.2MB)   -> total ~78.7 MB
    float* S     = (float*)d_ws;
    float* demod = (float*)((char*)d_ws + 4096);
    unsigned short* wT = (unsigned short*)((char*)d_ws + 8192);
    unsigned short* xT = (unsigned short*)((char*)d_ws + 9445376);

    // zero the padded-NHWC input (border stays zero)
    hipMemsetAsync(xT, 0, (size_t)B_ * HP * WP * CIN * 2, stream);

    compute_S_kernel<<<CIN, 256, 0, stream>>>(weight, S);
    compute_demod_kernel<<<B_, 256, 0, stream>>>(style, S, demod);
    compute_wmodT_kernel<<<B_ * 9 * COUT, 256, 0, stream>>>(weight, style, demod, wT);
    transpose_kernel<<<dim3(32, H_, B_), 256, 0, stream>>>(x, xT);

    conv_mfma_kernel<<<dim3((H_ / RT) * (W_ / CT), COUT / OCT, B_), 512, 0, stream>>>(
        xT, wT, out);
}

// Round 4
// 208.502 us; speedup vs baseline: 15.8449x; 1.0192x over previous
//
#include <hip/hip_runtime.h>
#include <hip/hip_bf16.h>

// Problem constants
#define B_    8
#define CIN   256
#define COUT  256
#define H_    128
#define W_    128
#define HP    130   // padded
#define WP    130

// Conv tile config: block = 128 oc x (16 rows x 32 cols), 512 thr / 8 waves.
// Wave = 64 oc x (8 rows x 16 cols): m=4 x n=8 frags of 16x16x32.
#define OCT   128
#define TROWS 16
#define TCOLS 32
#define XROWS 18    // TROWS + 2 halo
#define XCOLS 34    // TCOLS + 2 halo
// X tile: 18*34 pixels x 4 slots(8ch) = 2448 16B chunks; padded to 2560 (5/wave)
#define XCHUNKS_PAD 2560

using bfrag = __attribute__((ext_vector_type(8))) short;   // 8 bf16 (4 VGPRs)
using f32x4 = __attribute__((ext_vector_type(4))) float;   // 4 fp32 acc

#define ASM_VMCNT(n) asm volatile("s_waitcnt vmcnt(" #n ")" ::: "memory")
#define ASM_LGKM0()  asm volatile("s_waitcnt lgkmcnt(0)" ::: "memory")

__device__ __forceinline__ float leaky(float v) {
    return v >= 0.f ? v : 0.2f * v;
}

__device__ __forceinline__ unsigned short to_bf16(float v) {
    __hip_bfloat16 h = __float2bfloat16(v);
    return *(unsigned short*)&h;
}

// ---------------------------------------------------------------------------
// S[i][kw] = sum_{o,kh} weight[o,i,kh,kw]^2          (grid = CIN, 256 thr)
__global__ void compute_S_kernel(const float* __restrict__ weight, float* __restrict__ S) {
    const int i = blockIdx.x;
    const int t = threadIdx.x;     // = o
    const float* wp = weight + ((size_t)t * CIN + i) * 9;
    float s0 = 0.f, s1 = 0.f, s2 = 0.f;
#pragma unroll
    for (int kh = 0; kh < 3; ++kh) {
        float a = wp[kh * 3 + 0], b = wp[kh * 3 + 1], c = wp[kh * 3 + 2];
        s0 = fmaf(a, a, s0); s1 = fmaf(b, b, s1); s2 = fmaf(c, c, s2);
    }
    __shared__ float red[3][256];
    red[0][t] = s0; red[1][t] = s1; red[2][t] = s2;
    __syncthreads();
    for (int off = 128; off > 0; off >>= 1) {
        if (t < off) {
            red[0][t] += red[0][t + off];
            red[1][t] += red[1][t + off];
            red[2][t] += red[2][t + off];
        }
        __syncthreads();
    }
    if (t == 0) {
        S[i * 3 + 0] = red[0][0];
        S[i * 3 + 1] = red[1][0];
        S[i * 3 + 2] = red[2][0];
    }
}

// demod[b][kw] = rsqrt(sum_i style[b,i]^2 * S[i,kw] + 1e-8)   (grid = B)
__global__ void compute_demod_kernel(const float* __restrict__ style,
                                     const float* __restrict__ S,
                                     float* __restrict__ demod) {
    const int b = blockIdx.x;
    const int t = threadIdx.x;     // = i
    float sv = style[b * CIN + t];
    float sv2 = sv * sv;
    float s0 = sv2 * S[t * 3 + 0];
    float s1 = sv2 * S[t * 3 + 1];
    float s2 = sv2 * S[t * 3 + 2];
    __shared__ float red[3][256];
    red[0][t] = s0; red[1][t] = s1; red[2][t] = s2;
    __syncthreads();
    for (int off = 128; off > 0; off >>= 1) {
        if (t < off) {
            red[0][t] += red[0][t + off];
            red[1][t] += red[1][t + off];
            red[2][t] += red[2][t + off];
        }
        __syncthreads();
    }
    if (t == 0) {
        demod[b * 3 + 0] = rsqrtf(red[0][0] + 1e-8f);
        demod[b * 3 + 1] = rsqrtf(red[1][0] + 1e-8f);
        demod[b * 3 + 2] = rsqrtf(red[2][0] + 1e-8f);
    }
}

// wT[b][j][o][i] (bf16) = weight[o][i][j] * style[b][i] * demod[b][j%3]
__global__ void compute_wmodT_kernel(const float* __restrict__ weight,
                                     const float* __restrict__ style,
                                     const float* __restrict__ demod,
                                     unsigned short* __restrict__ wT) {
    const int bx = blockIdx.x;
    const int i  = threadIdx.x;
    const int o  = bx & (COUT - 1);
    const int j  = (bx >> 8) % 9;
    const int b  = bx / (9 * COUT);
    float w = weight[((size_t)o * CIN + i) * 9 + j];
    float m = style[b * CIN + i] * demod[b * 3 + (j % 3)];
    wT[(((size_t)(b * 9 + j) * COUT + o)) * CIN + i] = to_bf16(w * m);
}

// NCHW fp32 -> padded NHWC bf16 (interior): xT[b][h+1][w+1][i] = bf16(x[b][i][h][w])
__global__ __launch_bounds__(256) void transpose_kernel(const float* __restrict__ x,
                                                        unsigned short* __restrict__ xT) {
    const int bx = blockIdx.x;
    const int wtile = (bx & 3) * 32;
    const int itile = (bx >> 2) * 32;
    const int h = blockIdx.y;
    const int b = blockIdx.z;
    const int t = threadIdx.x;

    __shared__ float lt[32][33];

    {   // coalesced read: consecutive t -> consecutive w
        const int tw = t & 31, tr = t >> 5;
#pragma unroll
        for (int rr = 0; rr < 4; ++rr) {
            int il = tr + rr * 8;
            lt[il][tw] = x[(((size_t)b * CIN + itile + il) * H_ + h) * W_ + wtile + tw];
        }
    }
    __syncthreads();
    {   // coalesced write: consecutive t -> consecutive i
        const int il = t & 31, wr = t >> 5;
#pragma unroll
        for (int rr = 0; rr < 4; ++rr) {
            int wl = wr + rr * 8;
            xT[(((size_t)b * HP + (h + 1)) * WP + (wtile + wl + 1)) * CIN + itile + il] =
                to_bf16(lt[il][wl]);
        }
    }
}

// Zero only the padded border of xT (replaces 69MB memset).
// grid = dim3(8 b, 4 region), 256 thr. Regions: row0, row129, col0, col129.
__global__ void zero_border_kernel(unsigned short* __restrict__ xT) {
    const int b = blockIdx.x;
    const int r = blockIdx.y;
    const int t = threadIdx.x;
    int npix, base, stride;
    if (r == 0)      { npix = WP;  base = 0;                 stride = 1;  }
    else if (r == 1) { npix = WP;  base = (HP - 1) * WP;     stride = 1;  }
    else if (r == 2) { npix = 128; base = WP;                stride = WP; }
    else             { npix = 128; base = WP + (WP - 1);     stride = WP; }
    // per pixel: 256 ch * 2B = 512 B = 32 int4
    for (int idx = t; idx < npix * 32; idx += 256) {
        int p = idx >> 5, q = idx & 31;
        size_t off = ((size_t)b * HP * WP + base + (size_t)p * stride) * CIN;
        *(int4*)((unsigned short*)xT + off + q * 8) = (int4){0, 0, 0, 0};
    }
}

// ---------------------------------------------------------------------------
// Implicit-GEMM conv + leaky relu; counted-vmcnt pipeline (T3+T4+T5).
// A-tile [3kw][128oc][32i] triple-buffered (2-deep prefetch, global_load_lds).
// X-tile [18][34][32i] double-buffered (global_load_lds, 5 issues/wave/chunk).
// Per step (kh phase): issue A(s+2) [3/wave]; (kh==1: issue X(c+1) [5/wave]);
// compute; lgkmcnt(0); vmcnt(3/8/3); s_barrier. Tail kept uniform via
// clamped dummy loads into dead buffers. All per-wave schedules symmetric.
__global__ __launch_bounds__(512, 2) void conv_mfma_kernel(
    const unsigned short* __restrict__ xT,   // [8][130][130][256] bf16
    const unsigned short* __restrict__ wT,   // [8][9][256][256]  bf16
    float* __restrict__ out)
{
    const int tid = threadIdx.x;
    // XCD swizzle: lin%8 -> XCD (round-robin heuristic); give each XCD one b.
    const int lin = blockIdx.x + 32 * blockIdx.y + 64 * blockIdx.z;
    const int b   = lin & 7;
    const int rest = lin >> 3;            // 0..63
    const int pxt  = rest & 31;           // 0..31 pixel tile
    const int oc0  = (rest >> 5) * OCT;   // 0 or 128
    const int ph = pxt >> 2, pw = pxt & 3;
    const int h0 = ph * TROWS, w0 = pw * TCOLS;

    const int wid   = tid >> 6;               // 0..7
    const int lane  = tid & 63;
    const int wm    = wid >> 2;               // oc half (64 oc)
    const int rn    = (wid >> 1) & 1;         // row half (8 rows)
    const int cn    = wid & 1;                // col half (16 cols)
    const int l15   = lane & 15;
    const int khalf = lane >> 4;              // k-group 0..3

    __shared__ unsigned short lds_a[3][3 * OCT * 32];        // 3 x 24576 B
    __shared__ unsigned short lds_x[2][XCHUNKS_PAD * 8];     // 2 x 40960 B

    const unsigned short* xb = xT + ((size_t)(b * HP + h0) * WP + w0) * CIN;
    const unsigned short* wb = wT + ((size_t)(b * 9) * COUT + oc0) * CIN;

    // ---- per-thread precomputed source offsets (swizzled) ----
    int offA[3];
#pragma unroll
    for (int j = 0; j < 3; ++j) {
        int c    = (wid * 3 + j) * 64 + lane;          // 16B chunk in [0,1536)
        int slot = c & 3;
        int o    = (c >> 2) & 127;
        int kw   = c >> 9;
        offA[j] = (kw * COUT + o) * CIN + ((slot ^ ((o >> 1) & 3)) << 3);
    }
    int offX[5];
#pragma unroll
    for (int j = 0; j < 5; ++j) {
        int g  = (wid * 5 + j) * 64 + lane;            // [0,2560)
        int gg = g < 2448 ? g : 0;                     // clamp dummies
        int pix = gg >> 2, slot = gg & 3;
        int row = pix / XCOLS, col = pix - row * XCOLS;
        offX[j] = (row * WP + col) * CIN + ((slot ^ ((col >> 1) & 3)) << 3);
    }

    f32x4 acc[4][8];
#pragma unroll
    for (int m = 0; m < 4; ++m)
#pragma unroll
        for (int n = 0; n < 8; ++n) acc[m][n] = (f32x4){0.f, 0.f, 0.f, 0.f};

    // A-stage: 3 global_load_lds (16B) per thread; dest linear, src swizzled
    auto stage_A = [&](unsigned short* dst, const unsigned short* wsrc) {
#pragma unroll
        for (int j = 0; j < 3; ++j) {
            __builtin_amdgcn_global_load_lds(
                (const __attribute__((address_space(1))) void*)(wsrc + offA[j]),
                (__attribute__((address_space(3))) void*)(dst + (wid * 3 + j) * 512),
                16, 0, 0);
        }
    };
    // X-stage: 5 global_load_lds per thread (last partly lands in pad)
    auto stage_X = [&](unsigned short* dst, int i0) {
#pragma unroll
        for (int j = 0; j < 5; ++j) {
            __builtin_amdgcn_global_load_lds(
                (const __attribute__((address_space(1))) void*)(xb + offX[j] + i0),
                (__attribute__((address_space(3))) void*)(dst + (wid * 5 + j) * 512),
                16, 0, 0);
        }
    };

#define COMPUTE(KH, ABUF, XBUF)                                                        \
    {                                                                                  \
        const unsigned short* _ab = (ABUF);                                            \
        const unsigned short* _xb2 = (XBUF);                                           \
        __builtin_amdgcn_s_setprio(1);                                                 \
        _Pragma("unroll")                                                              \
        for (int kw = 0; kw < 3; ++kw) {                                               \
            bfrag aF[4];                                                               \
            _Pragma("unroll")                                                          \
            for (int m = 0; m < 4; ++m) {                                              \
                int oc = wm * 64 + m * 16 + l15;                                       \
                aF[m] = *(const bfrag*)&_ab[(kw * OCT + oc) * 32                       \
                          + ((khalf ^ ((oc >> 1) & 3)) << 3)];                         \
            }                                                                          \
            _Pragma("unroll")                                                          \
            for (int n = 0; n < 8; ++n) {                                              \
                int row = rn * 8 + n + (KH);                                           \
                int col = cn * 16 + l15 + kw;                                          \
                bfrag bF = *(const bfrag*)&_xb2[(row * XCOLS + col) * 32               \
                             + ((khalf ^ ((col >> 1) & 3)) << 3)];                     \
                _Pragma("unroll")                                                      \
                for (int m = 0; m < 4; ++m)                                            \
                    acc[m][n] = __builtin_amdgcn_mfma_f32_16x16x32_bf16(               \
                        aF[m], bF, acc[m][n], 0, 0, 0);                                \
            }                                                                          \
        }                                                                              \
        __builtin_amdgcn_s_setprio(0);                                                 \
    }

    const size_t KHS = (size_t)3 * COUT * CIN;   // j-stride per kh group

    // ---- prologue: A(0)->buf0, A(1)->buf1, X(0)->xbuf0; drain; barrier
    stage_A(lds_a[0], wb);
    stage_A(lds_a[1], wb + KHS);
    stage_X(lds_x[0], 0);
    ASM_VMCNT(0);
    __builtin_amdgcn_s_barrier();
    __builtin_amdgcn_sched_barrier(0);

#pragma unroll 1
    for (int c = 0; c < 8; ++c) {
        const int i0  = c * 32;
        const int i0n = ((c + 1) & 7) * 32;   // c=7 -> dummy (valid addr, dead buf)
        unsigned short* xcur = lds_x[c & 1];
        unsigned short* xnxt = lds_x[(c + 1) & 1];

        // ---- phase kh=0: issue A(c,kh2)->buf2; compute buf0
        stage_A(lds_a[2], wb + 2 * KHS + i0);
        COMPUTE(0, lds_a[0], xcur);
        ASM_LGKM0();
        ASM_VMCNT(3);
        __builtin_amdgcn_s_barrier();
        __builtin_amdgcn_sched_barrier(0);

        // ---- phase kh=1: issue A(c+1,kh0)->buf0, X(c+1); compute buf1
        stage_A(lds_a[0], wb + i0n);
        stage_X(xnxt, i0n);
        COMPUTE(1, lds_a[1], xcur);
        ASM_LGKM0();
        ASM_VMCNT(8);
        __builtin_amdgcn_s_barrier();
        __builtin_amdgcn_sched_barrier(0);

        // ---- phase kh=2: issue A(c+1,kh1)->buf1; compute buf2
        stage_A(lds_a[1], wb + KHS + i0n);
        COMPUTE(2, lds_a[2], xcur);
        ASM_LGKM0();
        ASM_VMCNT(3);
        __builtin_amdgcn_s_barrier();
        __builtin_amdgcn_sched_barrier(0);
    }
    ASM_VMCNT(0);   // drain tail dummies before stores

    // ---- epilogue: leaky relu + store (C/D: col=lane&15 -> pixel, row -> oc)
#pragma unroll
    for (int m = 0; m < 4; ++m) {
#pragma unroll
        for (int n = 0; n < 8; ++n) {
            int h = h0 + rn * 8 + n;
            int w = w0 + cn * 16 + l15;
#pragma unroll
            for (int r = 0; r < 4; ++r) {
                int oc = oc0 + wm * 64 + m * 16 + khalf * 4 + r;
                out[(((size_t)b * COUT + oc) * H_ + h) * W_ + w] = leaky(acc[m][n][r]);
            }
        }
    }
#undef COMPUTE
}

// ---------------------------------------------------------------------------
extern "C" void kernel_launch(void* const* d_in, const int* in_sizes, int n_in,
                              void* d_out, int out_size, void* d_ws, size_t ws_size,
                              hipStream_t stream) {
    const float* x      = (const float*)d_in[0];  // (8,256,128,128)
    const float* style  = (const float*)d_in[1];  // (8,256)
    const float* weight = (const float*)d_in[2];  // (256,256,3,3)
    float* out = (float*)d_out;                   // (8,256,128,128)

    // ws layout: S f32[768] @0 | demod f32[24] @4096 | wT bf16 @8192 (9.4MB)
    //            | xTpad bf16 @9445376 (69.2MB)   -> total ~78.7 MB
    float* S     = (float*)d_ws;
    float* demod = (float*)((char*)d_ws + 4096);
    unsigned short* wT = (unsigned short*)((char*)d_ws + 8192);
    unsigned short* xT = (unsigned short*)((char*)d_ws + 9445376);

    compute_S_kernel<<<CIN, 256, 0, stream>>>(weight, S);
    compute_demod_kernel<<<B_, 256, 0, stream>>>(style, S, demod);
    compute_wmodT_kernel<<<B_ * 9 * COUT, 256, 0, stream>>>(weight, style, demod, wT);
    transpose_kernel<<<dim3(32, H_, B_), 256, 0, stream>>>(x, xT);
    zero_border_kernel<<<dim3(B_, 4), 256, 0, stream>>>(xT);

    conv_mfma_kernel<<<dim3(32, 2, B_), 512, 0, stream>>>(xT, wT, out);
}

// Round 5
// 188.686 us; speedup vs baseline: 17.5090x; 1.1050x over previous
//
#include <hip/hip_runtime.h>
#include <hip/hip_bf16.h>

// Problem constants
#define B_    8
#define CIN   256
#define COUT  256
#define H_    128
#define W_    128
#define HP    130   // padded
#define WP    130

// Conv tile: block = 128 oc x (8 rows x 32 cols), 256 thr / 4 waves.
// Wave = 64 oc x (8 rows x 16 cols): m=4 x n=8 frags of 16x16x32.
#define OCT   128
#define TROWS 8
#define TCOLS 32
#define XROWS 10    // TROWS + 2 halo
#define XCOLS 34    // TCOLS + 2 halo
#define XCH   1360  // 10*34*4 real 16B chunks
#define XCHP  1536  // padded to 6/thread
#define NSTEP 24    // 8 cin-chunks x 3 kh
#define KHS   ((size_t)3 * COUT * CIN)

using bfrag = __attribute__((ext_vector_type(8))) short;   // 8 bf16 (4 VGPRs)
using f32x4 = __attribute__((ext_vector_type(4))) float;   // 4 fp32 acc

#define ASM_VMCNT(n) asm volatile("s_waitcnt vmcnt(" #n ")" ::: "memory")
#define ASM_LGKM0()  asm volatile("s_waitcnt lgkmcnt(0)" ::: "memory")

__device__ __forceinline__ float leaky(float v) {
    return v >= 0.f ? v : 0.2f * v;
}

__device__ __forceinline__ unsigned short to_bf16(float v) {
    __hip_bfloat16 h = __float2bfloat16(v);
    return *(unsigned short*)&h;
}

// ---------------------------------------------------------------------------
// S[i][kw] = sum_{o,kh} weight[o,i,kh,kw]^2          (grid = CIN, 256 thr)
__global__ void compute_S_kernel(const float* __restrict__ weight, float* __restrict__ S) {
    const int i = blockIdx.x;
    const int t = threadIdx.x;     // = o
    const float* wp = weight + ((size_t)t * CIN + i) * 9;
    float s0 = 0.f, s1 = 0.f, s2 = 0.f;
#pragma unroll
    for (int kh = 0; kh < 3; ++kh) {
        float a = wp[kh * 3 + 0], b = wp[kh * 3 + 1], c = wp[kh * 3 + 2];
        s0 = fmaf(a, a, s0); s1 = fmaf(b, b, s1); s2 = fmaf(c, c, s2);
    }
    __shared__ float red[3][256];
    red[0][t] = s0; red[1][t] = s1; red[2][t] = s2;
    __syncthreads();
    for (int off = 128; off > 0; off >>= 1) {
        if (t < off) {
            red[0][t] += red[0][t + off];
            red[1][t] += red[1][t + off];
            red[2][t] += red[2][t + off];
        }
        __syncthreads();
    }
    if (t == 0) {
        S[i * 3 + 0] = red[0][0];
        S[i * 3 + 1] = red[1][0];
        S[i * 3 + 2] = red[2][0];
    }
}

// demod[b][kw] = rsqrt(sum_i style[b,i]^2 * S[i,kw] + 1e-8)   (grid = B)
__global__ void compute_demod_kernel(const float* __restrict__ style,
                                     const float* __restrict__ S,
                                     float* __restrict__ demod) {
    const int b = blockIdx.x;
    const int t = threadIdx.x;     // = i
    float sv = style[b * CIN + t];
    float sv2 = sv * sv;
    float s0 = sv2 * S[t * 3 + 0];
    float s1 = sv2 * S[t * 3 + 1];
    float s2 = sv2 * S[t * 3 + 2];
    __shared__ float red[3][256];
    red[0][t] = s0; red[1][t] = s1; red[2][t] = s2;
    __syncthreads();
    for (int off = 128; off > 0; off >>= 1) {
        if (t < off) {
            red[0][t] += red[0][t + off];
            red[1][t] += red[1][t + off];
            red[2][t] += red[2][t + off];
        }
        __syncthreads();
    }
    if (t == 0) {
        demod[b * 3 + 0] = rsqrtf(red[0][0] + 1e-8f);
        demod[b * 3 + 1] = rsqrtf(red[1][0] + 1e-8f);
        demod[b * 3 + 2] = rsqrtf(red[2][0] + 1e-8f);
    }
}

// wT[b][j][o][i] (bf16) = weight[o][i][j] * style[b][i] * demod[b][j%3]
__global__ void compute_wmodT_kernel(const float* __restrict__ weight,
                                     const float* __restrict__ style,
                                     const float* __restrict__ demod,
                                     unsigned short* __restrict__ wT) {
    const int bx = blockIdx.x;
    const int i  = threadIdx.x;
    const int o  = bx & (COUT - 1);
    const int j  = (bx >> 8) % 9;
    const int b  = bx / (9 * COUT);
    float w = weight[((size_t)o * CIN + i) * 9 + j];
    float m = style[b * CIN + i] * demod[b * 3 + (j % 3)];
    wT[(((size_t)(b * 9 + j) * COUT + o)) * CIN + i] = to_bf16(w * m);
}

// NCHW fp32 -> padded NHWC bf16 (interior): xT[b][h+1][w+1][i] = bf16(x[b][i][h][w])
__global__ __launch_bounds__(256) void transpose_kernel(const float* __restrict__ x,
                                                        unsigned short* __restrict__ xT) {
    const int bx = blockIdx.x;
    const int wtile = (bx & 3) * 32;
    const int itile = (bx >> 2) * 32;
    const int h = blockIdx.y;
    const int b = blockIdx.z;
    const int t = threadIdx.x;

    __shared__ float lt[32][33];

    {   // coalesced read: consecutive t -> consecutive w
        const int tw = t & 31, tr = t >> 5;
#pragma unroll
        for (int rr = 0; rr < 4; ++rr) {
            int il = tr + rr * 8;
            lt[il][tw] = x[(((size_t)b * CIN + itile + il) * H_ + h) * W_ + wtile + tw];
        }
    }
    __syncthreads();
    {   // coalesced write: consecutive t -> consecutive i
        const int il = t & 31, wr = t >> 5;
#pragma unroll
        for (int rr = 0; rr < 4; ++rr) {
            int wl = wr + rr * 8;
            xT[(((size_t)b * HP + (h + 1)) * WP + (wtile + wl + 1)) * CIN + itile + il] =
                to_bf16(lt[il][wl]);
        }
    }
}

// Zero only the padded border of xT.
__global__ void zero_border_kernel(unsigned short* __restrict__ xT) {
    const int b = blockIdx.x;
    const int r = blockIdx.y;
    const int t = threadIdx.x;
    int npix, base, stride;
    if (r == 0)      { npix = WP;  base = 0;                 stride = 1;  }
    else if (r == 1) { npix = WP;  base = (HP - 1) * WP;     stride = 1;  }
    else if (r == 2) { npix = 128; base = WP;                stride = WP; }
    else             { npix = 128; base = WP + (WP - 1);     stride = WP; }
    for (int idx = t; idx < npix * 32; idx += 256) {
        int p = idx >> 5, q = idx & 31;
        size_t off = ((size_t)b * HP * WP + base + (size_t)p * stride) * CIN;
        *(int4*)((unsigned short*)xT + off + q * 8) = (int4){0, 0, 0, 0};
    }
}

// ---------------------------------------------------------------------------
// Implicit-GEMM conv + leaky relu.
// 4-wave block, 73.7 KB LDS -> 2 blocks/CU (8 waves/CU at ~256 combined regs).
// A [3kw][128oc][32i] double-buffered (gload_lds, prefetch 1 step ahead).
// X [10][34][32i] single-buffered: issued after kh2's barrier; consumed at
// kh0 after {vmcnt(6) ; s_barrier} (per-wave vmcnt + barrier = all waves' X).
__global__ __launch_bounds__(256, 2) void conv_mfma_kernel(
    const unsigned short* __restrict__ xT,   // [8][130][130][256] bf16
    const unsigned short* __restrict__ wT,   // [8][9][256][256]  bf16
    float* __restrict__ out)
{
    const int tid = threadIdx.x;
    const int lin = blockIdx.x;               // 1024 blocks; lin&7 -> XCD = batch
    const int b    = lin & 7;
    const int rest = lin >> 3;                // 0..127
    const int oc0  = (rest & 1) * OCT;
    const int w0   = ((rest >> 1) & 3) * TCOLS;
    const int h0   = (rest >> 3) * TROWS;

    const int wid   = tid >> 6;               // 0..3
    const int lane  = tid & 63;
    const int wm    = wid >> 1;               // oc half (64 oc)
    const int cw    = wid & 1;                // col half (16 cols)
    const int l15   = lane & 15;
    const int khalf = lane >> 4;              // k-group 0..3

    __shared__ unsigned short lds_a[2][3 * OCT * 32];   // 2 x 24576 B
    __shared__ unsigned short lds_x[XCHP * 8];          // 24576 B (incl pad)

    const unsigned short* xb = xT + ((size_t)(b * HP + h0) * WP + w0) * CIN;
    const unsigned short* wb = wT + ((size_t)(b * 9) * COUT + oc0) * CIN;

    // ---- per-thread source offsets (swizzled), 6 chunks each ----
    int offA[6];
#pragma unroll
    for (int j = 0; j < 6; ++j) {
        int c    = (wid * 6 + j) * 64 + lane;          // [0,1536)
        int slot = c & 3;
        int o    = (c >> 2) & 127;
        int kw   = c >> 9;
        offA[j] = (kw * COUT + o) * CIN + ((slot ^ ((o >> 1) & 3)) << 3);
    }
    int offX[6];
#pragma unroll
    for (int j = 0; j < 6; ++j) {
        int g  = (wid * 6 + j) * 64 + lane;            // [0,1536)
        int gg = g < XCH ? g : 0;                      // clamp dummies
        int pix = gg >> 2, slot = gg & 3;
        int row = pix / XCOLS, col = pix - row * XCOLS;
        offX[j] = (row * WP + col) * CIN + ((slot ^ ((col >> 1) & 3)) << 3);
    }

    f32x4 acc[4][8];
#pragma unroll
    for (int m = 0; m < 4; ++m)
#pragma unroll
        for (int n = 0; n < 8; ++n) acc[m][n] = (f32x4){0.f, 0.f, 0.f, 0.f};

    auto stage_A = [&](unsigned short* dst, const unsigned short* wsrc) {
#pragma unroll
        for (int j = 0; j < 6; ++j) {
            __builtin_amdgcn_global_load_lds(
                (const __attribute__((address_space(1))) void*)(wsrc + offA[j]),
                (__attribute__((address_space(3))) void*)(dst + (wid * 6 + j) * 512),
                16, 0, 0);
        }
    };
    auto stage_X = [&](int i0) {
#pragma unroll
        for (int j = 0; j < 6; ++j) {
            __builtin_amdgcn_global_load_lds(
                (const __attribute__((address_space(1))) void*)(xb + offX[j] + i0),
                (__attribute__((address_space(3))) void*)(lds_x + (wid * 6 + j) * 512),
                16, 0, 0);
        }
    };

    auto compute = [&](int kh, const unsigned short* ab) {
        __builtin_amdgcn_s_setprio(1);
#pragma unroll
        for (int kw = 0; kw < 3; ++kw) {
            bfrag aF[4];
#pragma unroll
            for (int m = 0; m < 4; ++m) {
                int oc = wm * 64 + m * 16 + l15;
                aF[m] = *(const bfrag*)&ab[(kw * OCT + oc) * 32
                          + ((khalf ^ ((oc >> 1) & 3)) << 3)];
            }
#pragma unroll
            for (int n = 0; n < 8; ++n) {
                int row = n + kh;                       // 0..9
                int col = cw * 16 + l15 + kw;           // 0..33
                bfrag bF = *(const bfrag*)&lds_x[(row * XCOLS + col) * 32
                             + ((khalf ^ ((col >> 1) & 3)) << 3)];
#pragma unroll
                for (int m = 0; m < 4; ++m)
                    acc[m][n] = __builtin_amdgcn_mfma_f32_16x16x32_bf16(
                        aF[m], bF, acc[m][n], 0, 0, 0);
            }
        }
        __builtin_amdgcn_s_setprio(0);
    };

    // ---- prologue: X(0) + A(step 0); drain; barrier
    stage_X(0);
    stage_A(lds_a[0], wb);
    ASM_VMCNT(0);
    __builtin_amdgcn_s_barrier();
    __builtin_amdgcn_sched_barrier(0);

#pragma unroll 1
    for (int s = 0; s < NSTEP; ++s) {
        const int c  = s / 3;
        const int kh = s - 3 * c;
        unsigned short* acur = lds_a[s & 1];
        unsigned short* anxt = lds_a[(s + 1) & 1];

        if (s < NSTEP - 1) {                       // prefetch A(s+1)
            const int sn = s + 1;
            const int cn2 = sn / 3;
            const int khn = sn - 3 * cn2;
            stage_A(anxt, wb + (size_t)khn * KHS + cn2 * 32);
        }
        if (kh == 0) {
            // own X issues landed (oldest 6 of <=12 outstanding); then all waves'
            ASM_VMCNT(6);
            __builtin_amdgcn_s_barrier();
            __builtin_amdgcn_sched_barrier(0);
        }
        compute(kh, acur);
        ASM_LGKM0();                               // X/A reads retired
        ASM_VMCNT(0);                              // A(s+1) landed (issued ~2k cy ago)
        __builtin_amdgcn_s_barrier();
        __builtin_amdgcn_sched_barrier(0);
        if (kh == 2 && s < NSTEP - 1)              // X buffer free: issue next chunk
            stage_X((c + 1) * 32);
    }

    // ---- epilogue: leaky relu + store (C/D: col=lane&15 -> pixel, row -> oc)
#pragma unroll
    for (int m = 0; m < 4; ++m) {
#pragma unroll
        for (int n = 0; n < 8; ++n) {
            int h = h0 + n;
            int w = w0 + cw * 16 + l15;
#pragma unroll
            for (int r = 0; r < 4; ++r) {
                int oc = oc0 + wm * 64 + m * 16 + khalf * 4 + r;
                out[(((size_t)b * COUT + oc) * H_ + h) * W_ + w] = leaky(acc[m][n][r]);
            }
        }
    }
}

// ---------------------------------------------------------------------------
extern "C" void kernel_launch(void* const* d_in, const int* in_sizes, int n_in,
                              void* d_out, int out_size, void* d_ws, size_t ws_size,
                              hipStream_t stream) {
    const float* x      = (const float*)d_in[0];  // (8,256,128,128)
    const float* style  = (const float*)d_in[1];  // (8,256)
    const float* weight = (const float*)d_in[2];  // (256,256,3,3)
    float* out = (float*)d_out;                   // (8,256,128,128)

    // ws layout: S f32[768] @0 | demod f32[24] @4096 | wT bf16 @8192 (9.4MB)
    //            | xTpad bf16 @9445376 (69.2MB)   -> total ~78.7 MB
    float* S     = (float*)d_ws;
    float* demod = (float*)((char*)d_ws + 4096);
    unsigned short* wT = (unsigned short*)((char*)d_ws + 8192);
    unsigned short* xT = (unsigned short*)((char*)d_ws + 9445376);

    compute_S_kernel<<<CIN, 256, 0, stream>>>(weight, S);
    compute_demod_kernel<<<B_, 256, 0, stream>>>(style, S, demod);
    compute_wmodT_kernel<<<B_ * 9 * COUT, 256, 0, stream>>>(weight, style, demod, wT);
    transpose_kernel<<<dim3(32, H_, B_), 256, 0, stream>>>(x, xT);
    zero_border_kernel<<<dim3(B_, 4), 256, 0, stream>>>(xT);

    conv_mfma_kernel<<<dim3(1024), 256, 0, stream>>>(xT, wT, out);
}

// Round 6
// 184.715 us; speedup vs baseline: 17.8854x; 1.0215x over previous
//
#include <hip/hip_runtime.h>
#include <hip/hip_bf16.h>

// Problem constants
#define B_    8
#define CIN   256
#define COUT  256
#define H_    128
#define W_    128
#define HP    130   // padded
#define WP    130

// Conv tile: block = 128 oc x (8 rows x 32 cols), 256 thr / 4 waves.
// Wave = 64 oc x (8 rows x 16 cols): m=4 x n=8 frags of 16x16x32.
#define OCT   128
#define TROWS 8
#define TCOLS 32
#define XROWS 10    // TROWS + 2 halo
#define XCOLS 34    // TCOLS + 2 halo
#define XCH   1360  // 10*34*4 real 16B chunks
#define XCHP  1536  // padded to 6/thread
#define KHS   ((size_t)3 * COUT * CIN)

using bfrag = __attribute__((ext_vector_type(8))) short;   // 8 bf16 (4 VGPRs)
using f32x4 = __attribute__((ext_vector_type(4))) float;   // 4 fp32 acc

#define ASM_VMCNT(n) asm volatile("s_waitcnt vmcnt(" #n ")" ::: "memory")
#define ASM_LGKM0()  asm volatile("s_waitcnt lgkmcnt(0)" ::: "memory")

__device__ __forceinline__ float leaky(float v) {
    return v >= 0.f ? v : 0.2f * v;
}

__device__ __forceinline__ unsigned short to_bf16(float v) {
    __hip_bfloat16 h = __float2bfloat16(v);
    return *(unsigned short*)&h;
}

// ---------------------------------------------------------------------------
// S[i][kw] = sum_{o,kh} weight[o,i,kh,kw]^2          (grid = CIN, 256 thr)
__global__ void compute_S_kernel(const float* __restrict__ weight, float* __restrict__ S) {
    const int i = blockIdx.x;
    const int t = threadIdx.x;     // = o
    const float* wp = weight + ((size_t)t * CIN + i) * 9;
    float s0 = 0.f, s1 = 0.f, s2 = 0.f;
#pragma unroll
    for (int kh = 0; kh < 3; ++kh) {
        float a = wp[kh * 3 + 0], b = wp[kh * 3 + 1], c = wp[kh * 3 + 2];
        s0 = fmaf(a, a, s0); s1 = fmaf(b, b, s1); s2 = fmaf(c, c, s2);
    }
    __shared__ float red[3][256];
    red[0][t] = s0; red[1][t] = s1; red[2][t] = s2;
    __syncthreads();
    for (int off = 128; off > 0; off >>= 1) {
        if (t < off) {
            red[0][t] += red[0][t + off];
            red[1][t] += red[1][t + off];
            red[2][t] += red[2][t + off];
        }
        __syncthreads();
    }
    if (t == 0) {
        S[i * 3 + 0] = red[0][0];
        S[i * 3 + 1] = red[1][0];
        S[i * 3 + 2] = red[2][0];
    }
}

// demod[b][kw] = rsqrt(sum_i style[b,i]^2 * S[i,kw] + 1e-8)   (grid = B)
__global__ void compute_demod_kernel(const float* __restrict__ style,
                                     const float* __restrict__ S,
                                     float* __restrict__ demod) {
    const int b = blockIdx.x;
    const int t = threadIdx.x;     // = i
    float sv = style[b * CIN + t];
    float sv2 = sv * sv;
    float s0 = sv2 * S[t * 3 + 0];
    float s1 = sv2 * S[t * 3 + 1];
    float s2 = sv2 * S[t * 3 + 2];
    __shared__ float red[3][256];
    red[0][t] = s0; red[1][t] = s1; red[2][t] = s2;
    __syncthreads();
    for (int off = 128; off > 0; off >>= 1) {
        if (t < off) {
            red[0][t] += red[0][t + off];
            red[1][t] += red[1][t + off];
            red[2][t] += red[2][t + off];
        }
        __syncthreads();
    }
    if (t == 0) {
        demod[b * 3 + 0] = rsqrtf(red[0][0] + 1e-8f);
        demod[b * 3 + 1] = rsqrtf(red[1][0] + 1e-8f);
        demod[b * 3 + 2] = rsqrtf(red[2][0] + 1e-8f);
    }
}

// wT[b][j][o][i] (bf16) = weight[o][i][j] * style[b][i] * demod[b][j%3]
__global__ void compute_wmodT_kernel(const float* __restrict__ weight,
                                     const float* __restrict__ style,
                                     const float* __restrict__ demod,
                                     unsigned short* __restrict__ wT) {
    const int bx = blockIdx.x;
    const int i  = threadIdx.x;
    const int o  = bx & (COUT - 1);
    const int j  = (bx >> 8) % 9;
    const int b  = bx / (9 * COUT);
    float w = weight[((size_t)o * CIN + i) * 9 + j];
    float m = style[b * CIN + i] * demod[b * 3 + (j % 3)];
    wT[(((size_t)(b * 9 + j) * COUT + o)) * CIN + i] = to_bf16(w * m);
}

// NCHW fp32 -> padded NHWC bf16 (interior): xT[b][h+1][w+1][i] = bf16(x[b][i][h][w])
__global__ __launch_bounds__(256) void transpose_kernel(const float* __restrict__ x,
                                                        unsigned short* __restrict__ xT) {
    const int bx = blockIdx.x;
    const int wtile = (bx & 3) * 32;
    const int itile = (bx >> 2) * 32;
    const int h = blockIdx.y;
    const int b = blockIdx.z;
    const int t = threadIdx.x;

    __shared__ float lt[32][33];

    {   // coalesced read: consecutive t -> consecutive w
        const int tw = t & 31, tr = t >> 5;
#pragma unroll
        for (int rr = 0; rr < 4; ++rr) {
            int il = tr + rr * 8;
            lt[il][tw] = x[(((size_t)b * CIN + itile + il) * H_ + h) * W_ + wtile + tw];
        }
    }
    __syncthreads();
    {   // coalesced write: consecutive t -> consecutive i
        const int il = t & 31, wr = t >> 5;
#pragma unroll
        for (int rr = 0; rr < 4; ++rr) {
            int wl = wr + rr * 8;
            xT[(((size_t)b * HP + (h + 1)) * WP + (wtile + wl + 1)) * CIN + itile + il] =
                to_bf16(lt[il][wl]);
        }
    }
}

// Zero only the padded border of xT.
__global__ void zero_border_kernel(unsigned short* __restrict__ xT) {
    const int b = blockIdx.x;
    const int r = blockIdx.y;
    const int t = threadIdx.x;
    int npix, base, stride;
    if (r == 0)      { npix = WP;  base = 0;                 stride = 1;  }
    else if (r == 1) { npix = WP;  base = (HP - 1) * WP;     stride = 1;  }
    else if (r == 2) { npix = 128; base = WP;                stride = WP; }
    else             { npix = 128; base = WP + (WP - 1);     stride = WP; }
    for (int idx = t; idx < npix * 32; idx += 256) {
        int p = idx >> 5, q = idx & 31;
        size_t off = ((size_t)b * HP * WP + base + (size_t)p * stride) * CIN;
        *(int4*)((unsigned short*)xT + off + q * 8) = (int4){0, 0, 0, 0};
    }
}

// ---------------------------------------------------------------------------
// Implicit-GEMM conv + leaky relu.
// 4-wave block, 73.7 KB LDS, 2 blocks/CU. Counted-vmcnt A double-buffer.
// Compute: 24 unrolled groups, each {1-2 ds_read_b128 (2-ahead prefetch) +
// 4 MFMA}, sched_group_barrier-enforced, so each wave overlaps its own LDS
// reads with MFMA (fixes the read-burst/MFMA-burst oscillation of r5).
__global__ __launch_bounds__(256, 2) void conv_mfma_kernel(
    const unsigned short* __restrict__ xT,   // [8][130][130][256] bf16
    const unsigned short* __restrict__ wT,   // [8][9][256][256]  bf16
    float* __restrict__ out)
{
    const int tid = threadIdx.x;
    const int lin = blockIdx.x;               // 1024 blocks; lin&7 -> XCD = batch
    const int b    = lin & 7;
    const int rest = lin >> 3;                // 0..127
    const int oc0  = (rest & 1) * OCT;
    const int w0   = ((rest >> 1) & 3) * TCOLS;
    const int h0   = (rest >> 3) * TROWS;

    const int wid   = tid >> 6;               // 0..3
    const int lane  = tid & 63;
    const int wm    = wid >> 1;               // oc half (64 oc)
    const int cw    = wid & 1;                // col half (16 cols)
    const int l15   = lane & 15;
    const int khalf = lane >> 4;              // k-group 0..3

    __shared__ unsigned short lds_a[2][3 * OCT * 32];   // 2 x 24576 B
    __shared__ unsigned short lds_x[XCHP * 8];          // 24576 B (incl pad)

    const unsigned short* xb = xT + ((size_t)(b * HP + h0) * WP + w0) * CIN;
    const unsigned short* wb = wT + ((size_t)(b * 9) * COUT + oc0) * CIN;

    // ---- per-thread gload source offsets (swizzled), 6 chunks each ----
    int offA[6];
#pragma unroll
    for (int j = 0; j < 6; ++j) {
        int c    = (wid * 6 + j) * 64 + lane;          // [0,1536)
        int slot = c & 3;
        int o    = (c >> 2) & 127;
        int kw   = c >> 9;
        offA[j] = (kw * COUT + o) * CIN + ((slot ^ ((o >> 1) & 3)) << 3);
    }
    int offX[6];
#pragma unroll
    for (int j = 0; j < 6; ++j) {
        int g  = (wid * 6 + j) * 64 + lane;            // [0,1536)
        int gg = g < XCH ? g : 0;                      // clamp dummies
        int pix = gg >> 2, slot = gg & 3;
        int row = pix / XCOLS, col = pix - row * XCOLS;
        offX[j] = (row * WP + col) * CIN + ((slot ^ ((col >> 1) & 3)) << 3);
    }

    // ---- fragment read bases (element offsets into LDS tiles) ----
    // A: xor term (oc>>1)&3 == (l15>>1)&3 (independent of m, kw)
    const int aoff = (wm * 64 + l15) * 32 + ((khalf ^ ((l15 >> 1) & 3)) << 3);
    int boff[3];
#pragma unroll
    for (int kw = 0; kw < 3; ++kw) {
        int col = cw * 16 + l15 + kw;
        boff[kw] = col * 32 + ((khalf ^ ((col >> 1) & 3)) << 3);
    }

    f32x4 acc[4][8];
#pragma unroll
    for (int m = 0; m < 4; ++m)
#pragma unroll
        for (int n = 0; n < 8; ++n) acc[m][n] = (f32x4){0.f, 0.f, 0.f, 0.f};

    auto stage_A = [&](unsigned short* dst, const unsigned short* wsrc) {
#pragma unroll
        for (int j = 0; j < 6; ++j) {
            __builtin_amdgcn_global_load_lds(
                (const __attribute__((address_space(1))) void*)(wsrc + offA[j]),
                (__attribute__((address_space(3))) void*)(dst + (wid * 6 + j) * 512),
                16, 0, 0);
        }
    };
    auto stage_X = [&](int i0) {
#pragma unroll
        for (int j = 0; j < 6; ++j) {
            __builtin_amdgcn_global_load_lds(
                (const __attribute__((address_space(1))) void*)(xb + offX[j] + i0),
                (__attribute__((address_space(3))) void*)(lds_x + (wid * 6 + j) * 512),
                16, 0, 0);
        }
    };

    // ---- interleaved compute: 24 groups of {reads + 4 MFMA} ----
    // B-frags rotate through 3 slots, read 2 groups ahead; A-frags ping-pong
    // per kw pass, next pass's 4 frags loaded during groups n=1..4.
    auto compute = [&](int kh, const unsigned short* ab) {
        const unsigned short* ap = ab + aoff;
        const unsigned short* bp[3];
#pragma unroll
        for (int kw = 0; kw < 3; ++kw)
            bp[kw] = lds_x + (size_t)kh * XCOLS * 32 + boff[kw];

        bfrag aF[2][4];
        bfrag bs[3];
#pragma unroll
        for (int m = 0; m < 4; ++m)
            aF[0][m] = *(const bfrag*)(ap + (size_t)m * 16 * 32);
        bs[0] = *(const bfrag*)(bp[0]);
        bs[1] = *(const bfrag*)(bp[0] + (size_t)XCOLS * 32);
        __builtin_amdgcn_sched_group_barrier(0x100, 6, 0);   // 6 DS reads first

        __builtin_amdgcn_s_setprio(1);
#pragma unroll
        for (int g = 0; g < 24; ++g) {
            const int kw = g >> 3, n = g & 7;
            int nr = 0;
            if (g <= 21) {          // B read, 2 groups ahead
                const int k2 = g + 2, n2 = k2 & 7, kw2 = k2 >> 3;
                bs[k2 % 3] = *(const bfrag*)(bp[kw2] + (size_t)n2 * XCOLS * 32);
                ++nr;
            }
            if (n >= 1 && n <= 4 && kw < 2) {   // A frag for next kw pass
                const int mj = n - 1;
                aF[(kw + 1) & 1][mj] =
                    *(const bfrag*)(ap + ((size_t)(kw + 1) * 128 + mj * 16) * 32);
                ++nr;
            }
            if (nr == 1) __builtin_amdgcn_sched_group_barrier(0x100, 1, 0);
            if (nr == 2) __builtin_amdgcn_sched_group_barrier(0x100, 2, 0);
#pragma unroll
            for (int m = 0; m < 4; ++m)
                acc[m][n] = __builtin_amdgcn_mfma_f32_16x16x32_bf16(
                    aF[kw & 1][m], bs[g % 3], acc[m][n], 0, 0, 0);
            __builtin_amdgcn_sched_group_barrier(0x8, 4, 0);
        }
        __builtin_amdgcn_s_setprio(0);
    };

    // ---- prologue: issue X(0) + A(kh0,0); waits happen in phase 0
    stage_X(0);
    stage_A(lds_a[0], wb);

#define PHASE(KH, CUR, NXT, PRE_OFF)                                  \
    stage_A((NXT), wb + (PRE_OFF));                                   \
    ASM_VMCNT(6);                                                     \
    __builtin_amdgcn_s_barrier();                                     \
    __builtin_amdgcn_sched_barrier(0);                                \
    compute((KH), (CUR));                                             \
    ASM_LGKM0();                                                      \
    __builtin_amdgcn_s_barrier();                                     \
    __builtin_amdgcn_sched_barrier(0);

#pragma unroll 1
    for (int c = 0; c < 8; ++c) {
        unsigned short* pa = lds_a[c & 1];
        unsigned short* pb = lds_a[(c & 1) ^ 1];
        const size_t i0  = (size_t)c * 32;
        const size_t i0n = (size_t)((c + 1) & 7) * 32;  // c=7 -> dummy chunk 0

        PHASE(0, pa, pb, KHS + i0)          // prefetch A(kh1,c)
        PHASE(1, pb, pa, 2 * KHS + i0)      // prefetch A(kh2,c)
        PHASE(2, pa, pb, i0n)               // prefetch A(kh0,c+1) (dummy at c=7)
        if (c < 7) stage_X((int)i0n);       // X buffer free after kh2 barrier
    }
#undef PHASE
    ASM_VMCNT(0);   // drain tail dummy before exit

    // ---- epilogue: leaky relu + store (C/D: col=lane&15 -> pixel, row -> oc)
#pragma unroll
    for (int m = 0; m < 4; ++m) {
#pragma unroll
        for (int n = 0; n < 8; ++n) {
            int h = h0 + n;
            int w = w0 + cw * 16 + l15;
#pragma unroll
            for (int r = 0; r < 4; ++r) {
                int oc = oc0 + wm * 64 + m * 16 + khalf * 4 + r;
                out[(((size_t)b * COUT + oc) * H_ + h) * W_ + w] = leaky(acc[m][n][r]);
            }
        }
    }
}

// ---------------------------------------------------------------------------
extern "C" void kernel_launch(void* const* d_in, const int* in_sizes, int n_in,
                              void* d_out, int out_size, void* d_ws, size_t ws_size,
                              hipStream_t stream) {
    const float* x      = (const float*)d_in[0];  // (8,256,128,128)
    const float* style  = (const float*)d_in[1];  // (8,256)
    const float* weight = (const float*)d_in[2];  // (256,256,3,3)
    float* out = (float*)d_out;                   // (8,256,128,128)

    // ws layout: S f32[768] @0 | demod f32[24] @4096 | wT bf16 @8192 (9.4MB)
    //            | xTpad bf16 @9445376 (69.2MB)   -> total ~78.7 MB
    float* S     = (float*)d_ws;
    float* demod = (float*)((char*)d_ws + 4096);
    unsigned short* wT = (unsigned short*)((char*)d_ws + 8192);
    unsigned short* xT = (unsigned short*)((char*)d_ws + 9445376);

    compute_S_kernel<<<CIN, 256, 0, stream>>>(weight, S);
    compute_demod_kernel<<<B_, 256, 0, stream>>>(style, S, demod);
    compute_wmodT_kernel<<<B_ * 9 * COUT, 256, 0, stream>>>(weight, style, demod, wT);
    transpose_kernel<<<dim3(32, H_, B_), 256, 0, stream>>>(x, xT);
    zero_border_kernel<<<dim3(B_, 4), 256, 0, stream>>>(xT);

    conv_mfma_kernel<<<dim3(1024), 256, 0, stream>>>(xT, wT, out);
}

// Round 7
// 182.189 us; speedup vs baseline: 18.1334x; 1.0139x over previous
//
#include <hip/hip_runtime.h>
#include <hip/hip_bf16.h>

// Problem constants
#define B_    8
#define CIN   256
#define COUT  256
#define H_    128
#define W_    128
#define HP    130   // padded
#define WP    130

// Conv tile: block = 128 oc x (8 rows x 32 cols), 256 thr / 4 waves.
// Wave = 64 oc x (8 rows x 16 cols): m=4 x n=8 frags of 16x16x32.
// Phases are per-KW (not per-kh): each phase holds A[3kh][128oc][32i] and
// sweeps pixel rows 0..9 once, reusing each B-frag for all valid kh.
#define OCT   128
#define TROWS 8
#define TCOLS 32
#define XROWS 10    // TROWS + 2 halo
#define XCOLS 34    // TCOLS + 2 halo
#define XCH   1360  // 10*34*4 real 16B chunks
#define XCHP  1536  // padded to 6/thread
#define CCS   ((size_t)COUT * CIN)       // element stride per j (tap)

using bfrag = __attribute__((ext_vector_type(8))) short;   // 8 bf16 (4 VGPRs)
using f32x4 = __attribute__((ext_vector_type(4))) float;   // 4 fp32 acc

#define ASM_VMCNT(n) asm volatile("s_waitcnt vmcnt(" #n ")" ::: "memory")
#define ASM_LGKM0()  asm volatile("s_waitcnt lgkmcnt(0)" ::: "memory")

__device__ __forceinline__ float leaky(float v) {
    return v >= 0.f ? v : 0.2f * v;
}

__device__ __forceinline__ unsigned short to_bf16(float v) {
    __hip_bfloat16 h = __float2bfloat16(v);
    return *(unsigned short*)&h;
}

// ---------------------------------------------------------------------------
// S[i][kw] = sum_{o,kh} weight[o,i,kh,kw]^2          (grid = CIN, 256 thr)
__global__ void compute_S_kernel(const float* __restrict__ weight, float* __restrict__ S) {
    const int i = blockIdx.x;
    const int t = threadIdx.x;     // = o
    const float* wp = weight + ((size_t)t * CIN + i) * 9;
    float s0 = 0.f, s1 = 0.f, s2 = 0.f;
#pragma unroll
    for (int kh = 0; kh < 3; ++kh) {
        float a = wp[kh * 3 + 0], b = wp[kh * 3 + 1], c = wp[kh * 3 + 2];
        s0 = fmaf(a, a, s0); s1 = fmaf(b, b, s1); s2 = fmaf(c, c, s2);
    }
    __shared__ float red[3][256];
    red[0][t] = s0; red[1][t] = s1; red[2][t] = s2;
    __syncthreads();
    for (int off = 128; off > 0; off >>= 1) {
        if (t < off) {
            red[0][t] += red[0][t + off];
            red[1][t] += red[1][t + off];
            red[2][t] += red[2][t + off];
        }
        __syncthreads();
    }
    if (t == 0) {
        S[i * 3 + 0] = red[0][0];
        S[i * 3 + 1] = red[1][0];
        S[i * 3 + 2] = red[2][0];
    }
}

// demod[b][kw] = rsqrt(sum_i style[b,i]^2 * S[i,kw] + 1e-8)   (grid = B)
__global__ void compute_demod_kernel(const float* __restrict__ style,
                                     const float* __restrict__ S,
                                     float* __restrict__ demod) {
    const int b = blockIdx.x;
    const int t = threadIdx.x;     // = i
    float sv = style[b * CIN + t];
    float sv2 = sv * sv;
    float s0 = sv2 * S[t * 3 + 0];
    float s1 = sv2 * S[t * 3 + 1];
    float s2 = sv2 * S[t * 3 + 2];
    __shared__ float red[3][256];
    red[0][t] = s0; red[1][t] = s1; red[2][t] = s2;
    __syncthreads();
    for (int off = 128; off > 0; off >>= 1) {
        if (t < off) {
            red[0][t] += red[0][t + off];
            red[1][t] += red[1][t + off];
            red[2][t] += red[2][t + off];
        }
        __syncthreads();
    }
    if (t == 0) {
        demod[b * 3 + 0] = rsqrtf(red[0][0] + 1e-8f);
        demod[b * 3 + 1] = rsqrtf(red[1][0] + 1e-8f);
        demod[b * 3 + 2] = rsqrtf(red[2][0] + 1e-8f);
    }
}

// wT[b][j][o][i] (bf16) = weight[o][i][j] * style[b][i] * demod[b][j%3]
__global__ void compute_wmodT_kernel(const float* __restrict__ weight,
                                     const float* __restrict__ style,
                                     const float* __restrict__ demod,
                                     unsigned short* __restrict__ wT) {
    const int bx = blockIdx.x;
    const int i  = threadIdx.x;
    const int o  = bx & (COUT - 1);
    const int j  = (bx >> 8) % 9;
    const int b  = bx / (9 * COUT);
    float w = weight[((size_t)o * CIN + i) * 9 + j];
    float m = style[b * CIN + i] * demod[b * 3 + (j % 3)];
    wT[(((size_t)(b * 9 + j) * COUT + o)) * CIN + i] = to_bf16(w * m);
}

// NCHW fp32 -> padded NHWC bf16 (interior): xT[b][h+1][w+1][i] = bf16(x[b][i][h][w])
__global__ __launch_bounds__(256) void transpose_kernel(const float* __restrict__ x,
                                                        unsigned short* __restrict__ xT) {
    const int bx = blockIdx.x;
    const int wtile = (bx & 3) * 32;
    const int itile = (bx >> 2) * 32;
    const int h = blockIdx.y;
    const int b = blockIdx.z;
    const int t = threadIdx.x;

    __shared__ float lt[32][33];

    {   // coalesced read: consecutive t -> consecutive w
        const int tw = t & 31, tr = t >> 5;
#pragma unroll
        for (int rr = 0; rr < 4; ++rr) {
            int il = tr + rr * 8;
            lt[il][tw] = x[(((size_t)b * CIN + itile + il) * H_ + h) * W_ + wtile + tw];
        }
    }
    __syncthreads();
    {   // coalesced write: consecutive t -> consecutive i
        const int il = t & 31, wr = t >> 5;
#pragma unroll
        for (int rr = 0; rr < 4; ++rr) {
            int wl = wr + rr * 8;
            xT[(((size_t)b * HP + (h + 1)) * WP + (wtile + wl + 1)) * CIN + itile + il] =
                to_bf16(lt[il][wl]);
        }
    }
}

// Zero only the padded border of xT.
__global__ void zero_border_kernel(unsigned short* __restrict__ xT) {
    const int b = blockIdx.x;
    const int r = blockIdx.y;
    const int t = threadIdx.x;
    int npix, base, stride;
    if (r == 0)      { npix = WP;  base = 0;                 stride = 1;  }
    else if (r == 1) { npix = WP;  base = (HP - 1) * WP;     stride = 1;  }
    else if (r == 2) { npix = 128; base = WP;                stride = WP; }
    else             { npix = 128; base = WP + (WP - 1);     stride = WP; }
    for (int idx = t; idx < npix * 32; idx += 256) {
        int p = idx >> 5, q = idx & 31;
        size_t off = ((size_t)b * HP * WP + base + (size_t)p * stride) * CIN;
        *(int4*)((unsigned short*)xT + off + q * 8) = (int4){0, 0, 0, 0};
    }
}

// ---------------------------------------------------------------------------
// Implicit-GEMM conv + leaky relu. KW-phased row sweep:
// phase(kw,c): A[3kh][128oc][32i] in LDS (dbuf, counted-vmcnt prefetch);
// compute keeps 12 A-frags in regs and sweeps rows r=0..9 reading each
// B-frag ONCE (10 reads), firing acc[m][r-kh] += A[kh][m]*B(r) for valid kh.
// 22 ds_read/phase (was 36) for the same 96 MFMA -> LDS pipe at 57% of MFMA.
__global__ __launch_bounds__(256, 2) void conv_mfma_kernel(
    const unsigned short* __restrict__ xT,   // [8][130][130][256] bf16
    const unsigned short* __restrict__ wT,   // [8][9][256][256]  bf16
    float* __restrict__ out)
{
    const int tid = threadIdx.x;
    const int lin = blockIdx.x;               // 1024 blocks; lin&7 -> XCD = batch
    const int b    = lin & 7;
    const int rest = lin >> 3;                // 0..127
    const int oc0  = (rest & 1) * OCT;
    const int w0   = ((rest >> 1) & 3) * TCOLS;
    const int h0   = (rest >> 3) * TROWS;

    const int wid   = tid >> 6;               // 0..3
    const int lane  = tid & 63;
    const int wm    = wid >> 1;               // oc half (64 oc)
    const int cw    = wid & 1;                // col half (16 cols)
    const int l15   = lane & 15;
    const int khalf = lane >> 4;              // k-group 0..3

    __shared__ unsigned short lds_a[2][3 * OCT * 32];   // 2 x 24576 B ([kh][o][i])
    __shared__ unsigned short lds_x[XCHP * 8];          // 24576 B (incl pad)

    const unsigned short* xb = xT + ((size_t)(b * HP + h0) * WP + w0) * CIN;
    const unsigned short* wb = wT + ((size_t)(b * 9) * COUT + oc0) * CIN;

    // ---- per-thread gload source offsets (swizzled) ----
    // A chunk c16 = (wid*6+j)*64+lane covers [kh][o][slot]; kw/i0 via base ptr.
    int offA[6];
#pragma unroll
    for (int j = 0; j < 6; ++j) {
        int c    = (wid * 6 + j) * 64 + lane;          // [0,1536)
        int slot = c & 3;
        int o    = (c >> 2) & 127;
        int kh   = c >> 9;
        offA[j] = (int)((size_t)(kh * 3) * CCS) + o * CIN
                  + ((slot ^ ((o >> 1) & 3)) << 3);
    }

    f32x4 acc[4][8];
#pragma unroll
    for (int m = 0; m < 4; ++m)
#pragma unroll
        for (int n = 0; n < 8; ++n) acc[m][n] = (f32x4){0.f, 0.f, 0.f, 0.f};

    // A-stage for phase(kw, chunk): base = wb + kw*CCS + i0
    auto stage_A = [&](unsigned short* dst, const unsigned short* wsrc) {
#pragma unroll
        for (int j = 0; j < 6; ++j) {
            __builtin_amdgcn_global_load_lds(
                (const __attribute__((address_space(1))) void*)(wsrc + offA[j]),
                (__attribute__((address_space(3))) void*)(dst + (wid * 6 + j) * 512),
                16, 0, 0);
        }
    };
    // X-stage: offsets recomputed per call (saves 6 live VGPRs)
    auto stage_X = [&](int i0) {
#pragma unroll
        for (int j = 0; j < 6; ++j) {
            int g  = (wid * 6 + j) * 64 + lane;        // [0,1536)
            int gg = g < XCH ? g : 0;                  // clamp dummies
            int pix = gg >> 2, slot = gg & 3;
            int row = pix / XCOLS, col = pix - row * XCOLS;
            int ofx = (row * WP + col) * CIN + ((slot ^ ((col >> 1) & 3)) << 3);
            __builtin_amdgcn_global_load_lds(
                (const __attribute__((address_space(1))) void*)(xb + ofx + i0),
                (__attribute__((address_space(3))) void*)(lds_x + (wid * 6 + j) * 512),
                16, 0, 0);
        }
    };

    // ---- fragment read bases ----
    const int aoff = (wm * 64 + l15) * 32 + ((khalf ^ ((l15 >> 1) & 3)) << 3);

    // ---- kw-phase compute: 12 A-frags in regs, single row sweep r=0..9 ----
    auto compute = [&](int kw, const unsigned short* ab) {
        const int col = cw * 16 + l15 + kw;
        const unsigned short* bp = lds_x + col * 32 + ((khalf ^ ((col >> 1) & 3)) << 3);

        bfrag aF[3][4];
#pragma unroll
        for (int kh = 0; kh < 3; ++kh)
#pragma unroll
            for (int m = 0; m < 4; ++m)
                aF[kh][m] = *(const bfrag*)(ab + aoff + ((size_t)kh * 128 + m * 16) * 32);

        bfrag bs[3];
        bs[0] = *(const bfrag*)(bp);
        bs[1] = *(const bfrag*)(bp + (size_t)XCOLS * 32);

        __builtin_amdgcn_s_setprio(1);
#pragma unroll
        for (int r = 0; r < 10; ++r) {
            if (r < 8)
                bs[(r + 2) % 3] = *(const bfrag*)(bp + (size_t)(r + 2) * XCOLS * 32);
            const bfrag bv = bs[r % 3];
#pragma unroll
            for (int kh = 0; kh < 3; ++kh) {
                const int n = r - kh;
                if (n >= 0 && n < 8) {
#pragma unroll
                    for (int m = 0; m < 4; ++m)
                        acc[m][n] = __builtin_amdgcn_mfma_f32_16x16x32_bf16(
                            aF[kh][m], bv, acc[m][n], 0, 0, 0);
                }
            }
        }
        __builtin_amdgcn_s_setprio(0);
    };

    // ---- prologue: issue X(0) + A(kw0,c0); drain; barrier
    stage_X(0);
    stage_A(lds_a[0], wb);
    ASM_VMCNT(0);
    __builtin_amdgcn_s_barrier();
    __builtin_amdgcn_sched_barrier(0);

    // phase p = 3c+kw; compute from lds_a[p&1], prefetch into lds_a[(p+1)&1].
    // Steady-state ledger: vmcnt(6) leaves exactly the just-issued 6 A-loads.
#define PHASE(KW, CUR, NXT, PRE_OFF)                                  \
    stage_A((NXT), wb + (PRE_OFF));                                   \
    ASM_VMCNT(6);                                                     \
    __builtin_amdgcn_s_barrier();                                     \
    __builtin_amdgcn_sched_barrier(0);                                \
    compute((KW), (CUR));                                             \
    ASM_LGKM0();                                                      \
    __builtin_amdgcn_s_barrier();                                     \
    __builtin_amdgcn_sched_barrier(0);

#pragma unroll 1
    for (int c = 0; c < 8; ++c) {
        unsigned short* pa = lds_a[c & 1];        // phase parity: p=3c -> c&1
        unsigned short* pb = lds_a[(c & 1) ^ 1];
        const size_t i0  = (size_t)c * 32;
        const size_t i0n = (size_t)((c + 1) & 7) * 32;  // c=7 -> dummy chunk 0

        PHASE(0, pa, pb, 1 * CCS + i0)       // prefetch A(kw=1, c)
        PHASE(1, pb, pa, 2 * CCS + i0)       // prefetch A(kw=2, c)
        PHASE(2, pa, pb, i0n)                // prefetch A(kw=0, c+1) (dummy at c=7)
        if (c < 7) stage_X((int)i0n);        // X buffer free after kw2's barrier
    }
#undef PHASE
    ASM_VMCNT(0);   // drain tail dummy before exit

    // ---- epilogue: leaky relu + store (C/D: col=lane&15 -> pixel, row -> oc)
#pragma unroll
    for (int m = 0; m < 4; ++m) {
#pragma unroll
        for (int n = 0; n < 8; ++n) {
            int h = h0 + n;
            int w = w0 + cw * 16 + l15;
#pragma unroll
            for (int r = 0; r < 4; ++r) {
                int oc = oc0 + wm * 64 + m * 16 + khalf * 4 + r;
                out[(((size_t)b * COUT + oc) * H_ + h) * W_ + w] = leaky(acc[m][n][r]);
            }
        }
    }
}

// ---------------------------------------------------------------------------
extern "C" void kernel_launch(void* const* d_in, const int* in_sizes, int n_in,
                              void* d_out, int out_size, void* d_ws, size_t ws_size,
                              hipStream_t stream) {
    const float* x      = (const float*)d_in[0];  // (8,256,128,128)
    const float* style  = (const float*)d_in[1];  // (8,256)
    const float* weight = (const float*)d_in[2];  // (256,256,3,3)
    float* out = (float*)d_out;                   // (8,256,128,128)

    // ws layout: S f32[768] @0 | demod f32[24] @4096 | wT bf16 @8192 (9.4MB)
    //            | xTpad bf16 @9445376 (69.2MB)   -> total ~78.7 MB
    float* S     = (float*)d_ws;
    float* demod = (float*)((char*)d_ws + 4096);
    unsigned short* wT = (unsigned short*)((char*)d_ws + 8192);
    unsigned short* xT = (unsigned short*)((char*)d_ws + 9445376);

    compute_S_kernel<<<CIN, 256, 0, stream>>>(weight, S);
    compute_demod_kernel<<<B_, 256, 0, stream>>>(style, S, demod);
    compute_wmodT_kernel<<<B_ * 9 * COUT, 256, 0, stream>>>(weight, style, demod, wT);
    transpose_kernel<<<dim3(32, H_, B_), 256, 0, stream>>>(x, xT);
    zero_border_kernel<<<dim3(B_, 4), 256, 0, stream>>>(xT);

    conv_mfma_kernel<<<dim3(1024), 256, 0, stream>>>(xT, wT, out);
}